// Round 4
// baseline (935.803 us; speedup 1.0000x reference)
//
#include <hip/hip_runtime.h>
#include <math.h>

#define Bn 16
#define Gn 2048
#define Cn 128
#define Kn 16
#define QB 64       // queries per block
#define AS 136      // A-tile row stride in bf16 elems: 272B = 17*16B (aligned, 2-way banks)

typedef __attribute__((ext_vector_type(8))) short bf16x8;
typedef __attribute__((ext_vector_type(4))) float f32x4;

__device__ __forceinline__ unsigned short f2bf(float x) {   // RNE fp32->bf16
    unsigned int u = __float_as_uint(x);
    unsigned int r = (u + 0x7fffu + ((u >> 16) & 1u)) >> 16;
    return (unsigned short)r;
}
__device__ __forceinline__ float bf2f(unsigned short h) {
    return __uint_as_float(((unsigned int)h) << 16);
}

__device__ __forceinline__ float med3f(float a, float b, float c) {
#if __has_builtin(__builtin_amdgcn_fmed3f)
    return __builtin_amdgcn_fmed3f(a, b, c);
#else
    return fmaxf(fminf(a, b), fminf(fmaxf(a, b), c));
#endif
}

// BIT-IDENTICAL in every phase (fp-consistent ranking incl. tie detection).
__device__ __forceinline__ float dist2(const float4 me, const float4 p) {
    float dot = fmaf(me.z, p.z, fmaf(me.y, p.y, me.x * p.x));
    return fmaf(-2.0f, dot, me.w + p.w);
}

__device__ __forceinline__ void ins16(float (&d)[16], float v) {
    float prev = d[0];
    d[0] = fminf(d[0], v);
    #pragma unroll
    for (int t = 1; t < 16; ++t) { float cur = d[t]; d[t] = med3f(v, prev, cur); prev = cur; }
}

// exact bitonic min-merge of sorted d[16] across the 16 lanes of a group
__device__ __forceinline__ void merge16(float (&d)[16]) {
    #pragma unroll
    for (int m = 1; m < 16; m <<= 1) {
        float e[16];
        #pragma unroll
        for (int t = 0; t < 16; ++t) e[t] = __shfl_xor(d[t], m);
        float x[16];
        #pragma unroll
        for (int t = 0; t < 16; ++t) x[t] = fminf(d[t], e[15 - t]);
        #pragma unroll
        for (int k = 8; k; k >>= 1) {
            #pragma unroll
            for (int t = 0; t < 16; ++t)
                if (!(t & k)) {
                    float lo = fminf(x[t], x[t + k]);
                    float hi = fmaxf(x[t], x[t + k]);
                    x[t] = lo; x[t + k] = hi;
                }
        }
        #pragma unroll
        for (int t = 0; t < 16; ++t) d[t] = x[t];
    }
}

__device__ __forceinline__ float gelu_exact(float x) {
    return 0.5f * x * (1.0f + erff(x * 0.70710678118654752440f));
}

// ---------------------------------------------------------------------------
// prep_w: W[k][n] fp32 -> Wt[n][k] split bf16 (hi/lo) in workspace.
// ws layout (ushorts): Wt1_hi[128*128] | Wt1_lo | Wt2_hi | Wt2_lo  (128 KB)
// ---------------------------------------------------------------------------
__global__ __launch_bounds__(256) void prep_w(const float* __restrict__ W1,
                                              const float* __restrict__ W2,
                                              unsigned short* __restrict__ ws) {
    int t = blockIdx.x * 256 + threadIdx.x;     // 0..16383 (grid 64)
    if (t < 16384) {
        int k = t >> 7, n = t & 127;
        float w = W1[t];
        unsigned short h = f2bf(w);
        unsigned short l = f2bf(w - bf2f(h));   // Dekker split: w-hi exact in fp32
        ws[n * 128 + k]          = h;
        ws[16384 + n * 128 + k]  = l;
        w = W2[t];
        h = f2bf(w);
        l = f2bf(w - bf2f(h));
        ws[32768 + n * 128 + k]  = h;
        ws[49152 + n * 128 + k]  = l;
    }
}

// ---------------------------------------------------------------------------
// Fully fused: KNN (sample->filter->select) + gather/L2-pool + MFMA MLP.
// 512 blocks x 1024 threads (16 waves); b = x&15; chunk = x>>4; 64 q/block.
// 16 lanes per query; each lane owns a 128-point segment; survivors kept as
// a 4x u32 REGISTER bitmask (scan-order bits; decode h=base+((p+c)&127)).
// LDS 38912 B = pts 32KB | outb 2KB @34816 | tieb 2KB @36864; At[64][136]x2
// overlays bytes 0..34816 (pts dead, outb untouched above).
//   -> 2 blocks/CU x 16 waves = 32 waves/CU (8/SIMD, FULL occupancy).
// MLP: split-bf16 MFMA 16x16x32 (Ahi*Bhi + Ahi*Blo + Alo*Bhi, err ~2^-17).
// ---------------------------------------------------------------------------
__global__ __launch_bounds__(1024, 8) void fused_kernel(const float* __restrict__ xyz,
                                                        const float* __restrict__ feat,
                                                        const float* __restrict__ b1,
                                                        const float* __restrict__ b2,
                                                        const unsigned short* __restrict__ wt,
                                                        float* __restrict__ out) {
    __shared__ __align__(16) float smem0[9728];       // 38912 B
    float4* pts = reinterpret_cast<float4*>(smem0);   // [2048] xyz + |p|^2 (0..32768)
    unsigned short* Ahi = reinterpret_cast<unsigned short*>(smem0);  // [64][AS] 0..17408
    unsigned short* Alo = Ahi + QB * AS;                             // 17408..34816
    unsigned short* outb = reinterpret_cast<unsigned short*>(smem0) + 17408;  // byte 34816, [64][16]
    unsigned short* tieb = outb + QB * 16;                                    // byte 36864, [64][16]

    const int x     = blockIdx.x;
    const int b     = x & 15;
    const int chunk = x >> 4;                       // 0..31
    const int tid   = threadIdx.x;                  // 0..1023
    const int lane  = tid & 63;
    const int w     = tid >> 6;                     // 0..15
    const int sub   = lane & 15;                    // lane within 16-lane group
    const int qg    = lane >> 4;                    // query group within wave (0..3)
    const int q     = w * 4 + qg;                   // 0..63
    const int g     = chunk * QB + q;

    // ---- stage xyz + |p|^2
    const float* xb = xyz + (size_t)b * Gn * 3;
    for (int i = tid; i < Gn; i += 1024) {
        float px = xb[i * 3 + 0], py = xb[i * 3 + 1], pz = xb[i * 3 + 2];
        pts[i] = make_float4(px, py, pz, px * px + py * py + pz * pz);
    }
    __syncthreads();

    const float4 me = pts[g];
    const int base = sub << 7;                      // lane's 128-point segment
    const int c    = (37 * sub) & 127;              // bank stagger

    // ---- phase A: top16 of 512-sample (32/lane) -> conservative T0
    float d[16];
    #pragma unroll
    for (int t = 0; t < 16; ++t) d[t] = INFINITY;
    for (int j = 0; j < 32; j += 4) {
        float4 p0 = pts[base + ((j + 0 + c) & 127)];
        float4 p1 = pts[base + ((j + 1 + c) & 127)];
        float4 p2 = pts[base + ((j + 2 + c) & 127)];
        float4 p3 = pts[base + ((j + 3 + c) & 127)];
        ins16(d, dist2(me, p0)); ins16(d, dist2(me, p1));
        ins16(d, dist2(me, p2)); ins16(d, dist2(me, p3));
    }
    merge16(d);
    const float T0 = d[15];

    // ---- phase B: filter scan -> register bitmask (scan-order bits, exact)
    unsigned mw[4];
    #pragma unroll
    for (int wd = 0; wd < 4; ++wd) {
        unsigned m = 0;
        #pragma unroll
        for (int j = 0; j < 32; j += 4) {
            int t0 = wd * 32 + j;
            float4 p0 = pts[base + ((t0 + 0 + c) & 127)];
            float4 p1 = pts[base + ((t0 + 1 + c) & 127)];
            float4 p2 = pts[base + ((t0 + 2 + c) & 127)];
            float4 p3 = pts[base + ((t0 + 3 + c) & 127)];
            m |= (dist2(me, p0) <= T0) ? (1u << (j + 0)) : 0u;
            m |= (dist2(me, p1) <= T0) ? (1u << (j + 1)) : 0u;
            m |= (dist2(me, p2) <= T0) ? (1u << (j + 2)) : 0u;
            m |= (dist2(me, p3) <= T0) ? (1u << (j + 3)) : 0u;
        }
        mw[wd] = m;
    }
    unsigned long long blo = mw[0] | ((unsigned long long)mw[1] << 32);
    unsigned long long bhi = mw[2] | ((unsigned long long)mw[3] << 32);

    // ---- phase C: exact top16 of survivors (own bits, no cross-lane) -> exact T
    #pragma unroll
    for (int t = 0; t < 16; ++t) d[t] = INFINITY;
    {
        unsigned long long m = blo;
        while (m) {
            int p = __builtin_ctzll(m); m &= m - 1;
            int h = base + ((p + c) & 127);
            ins16(d, dist2(me, pts[h]));
        }
        m = bhi;
        while (m) {
            int p = 64 + __builtin_ctzll(m); m &= m - 1;
            int h = base + ((p + c) & 127);
            ins16(d, dist2(me, pts[h]));
        }
    }
    merge16(d);
    const float T = d[15];

    // ---- phase D: emit index set (group-max rounds, INF padding; ballots)
    int myc = __popcll(blo) + __popcll(bhi);
    int mymax = myc;
    #pragma unroll
    for (int m = 1; m < 16; m <<= 1) {
        int o = __shfl_xor(mymax, m);
        mymax = (o > mymax) ? o : mymax;
    }
    const unsigned lowm = (1u << sub) - 1;
    const int shft = lane & 48;                     // group base bit
    int nl = 0, nt = 0;
    for (int i = 0; i < mymax; ++i) {
        int h = 0; float v = INFINITY;
        if ((blo | bhi) != 0ull) {
            int p;
            if (blo) { p = __builtin_ctzll(blo); blo &= blo - 1; }
            else     { p = 64 + __builtin_ctzll(bhi); bhi &= bhi - 1; }
            h = base + ((p + c) & 127);
            v = dist2(me, pts[h]);
        }
        bool pl = (v < T), pt = (v == T);
        unsigned long long ml = __ballot(pl);
        unsigned long long mt = __ballot(pt);
        unsigned gml = (unsigned)(ml >> shft) & 0xFFFFu;
        unsigned gmt = (unsigned)(mt >> shft) & 0xFFFFu;
        if (pl) outb[q * 16 + nl + __popc(gml & lowm)] = (unsigned short)h;  // nl_total <= 15
        if (pt) { int pp = nt + __popc(gmt & lowm); if (pp < 16) tieb[q * 16 + pp] = (unsigned short)h; }
        nl += __popc(gml);
        nt += __popc(gmt);
    }
    if (sub == 0) {
        int mfill = nl;                              // < 16
        int need  = 16 - mfill;
        int tc = (nt > 16) ? 16 : nt;
        for (int s = 0; s < need; ++s) {
            int best = 0x7fffffff, bp = -1;
            for (int u = 0; u < tc; ++u) {
                int vv = tieb[q * 16 + u];
                if (vv < best) { best = vv; bp = u; }
            }
            if (bp >= 0) { tieb[q * 16 + bp] = 0xFFFF; outb[q * 16 + mfill + s] = (unsigned short)best; }
        }
    }
    __syncthreads();                                 // pts dead; outb ready (above At window)

    // ---- gather + L2 pool: half-wave per query, float4 lanes (512B coalesced)
    // write pooled A directly as split-bf16 into Ahi/Alo (overlays pts region)
    const float4* fb4 = (const float4*)(feat + (size_t)b * Gn * Cn);
    const int cl = lane & 31;
    #pragma unroll
    for (int pass = 0; pass < 2; ++pass) {
        int qq = w * 4 + pass * 2 + (lane >> 5);
        float4 a = make_float4(0.f, 0.f, 0.f, 0.f);
        #pragma unroll
        for (int half = 0; half < 2; ++half) {
            int hs[8]; float4 f[8];
            #pragma unroll
            for (int k = 0; k < 8; ++k) hs[k] = outb[qq * 16 + half * 8 + k];
            #pragma unroll
            for (int k = 0; k < 8; ++k) f[k] = fb4[(size_t)hs[k] * 32 + cl];
            #pragma unroll
            for (int k = 0; k < 8; ++k) {
                a.x = fmaf(f[k].x, f[k].x, a.x);
                a.y = fmaf(f[k].y, f[k].y, a.y);
                a.z = fmaf(f[k].z, f[k].z, a.z);
                a.w = fmaf(f[k].w, f[k].w, a.w);
            }
        }
        float r0 = sqrtf(a.x), r1 = sqrtf(a.y), r2 = sqrtf(a.z), r3 = sqrtf(a.w);
        unsigned short h0 = f2bf(r0), h1 = f2bf(r1), h2 = f2bf(r2), h3 = f2bf(r3);
        ushort4 hv = make_ushort4(h0, h1, h2, h3);
        ushort4 lv = make_ushort4(f2bf(r0 - bf2f(h0)), f2bf(r1 - bf2f(h1)),
                                  f2bf(r2 - bf2f(h2)), f2bf(r3 - bf2f(h3)));
        *(ushort4*)&Ahi[qq * AS + cl * 4] = hv;
        *(ushort4*)&Alo[qq * AS + cl * 4] = lv;
    }
    __syncthreads();

    // ---- MLP via split-bf16 MFMA ------------------------------------------
    // wave w: rows rowg..rowg+15 (rowg=(w&3)*16), cols colg0..colg0+31
    // A-frag: lane l -> A[rowg+(l&15)][kk + (l>>4)*8 + j]  (contiguous bf16x8)
    // B-frag: lane l -> Wt[colg0+cb*16+(l&15)][kk + (l>>4)*8 + j] (contiguous)
    // C/D:    lane l, reg r -> C[(l>>4)*4 + r][l&15]   (m89-verified)
    const int l15  = lane & 15;
    const int kofs = (lane >> 4) * 8;
    const int rowg = (w & 3) * 16;
    const int colg0 = (w >> 2) * 32;
    const unsigned short* wt1h = wt;            // +16384: lo; +32768: W2 hi; +49152: W2 lo
    f32x4 acc[2];

    // ---- layer 1: h = gelu(pooled @ W1 + b1)
    #pragma unroll
    for (int cb = 0; cb < 2; ++cb) {
        float bv = b1[colg0 + cb * 16 + l15];
        acc[cb] = (f32x4){bv, bv, bv, bv};
    }
    #pragma unroll
    for (int kk = 0; kk < 128; kk += 32) {
        bf16x8 ah = *(const bf16x8*)&Ahi[rowg * AS + l15 * AS + kk + kofs];
        bf16x8 al = *(const bf16x8*)&Alo[rowg * AS + l15 * AS + kk + kofs];
        #pragma unroll
        for (int cb = 0; cb < 2; ++cb) {
            const unsigned short* wp = wt1h + (size_t)(colg0 + cb * 16 + l15) * 128 + kk + kofs;
            bf16x8 bh = *(const bf16x8*)wp;
            bf16x8 bl = *(const bf16x8*)(wp + 16384);
            acc[cb] = __builtin_amdgcn_mfma_f32_16x16x32_bf16(ah, bh, acc[cb], 0, 0, 0);
            acc[cb] = __builtin_amdgcn_mfma_f32_16x16x32_bf16(ah, bl, acc[cb], 0, 0, 0);
            acc[cb] = __builtin_amdgcn_mfma_f32_16x16x32_bf16(al, bh, acc[cb], 0, 0, 0);
        }
    }
    __syncthreads();                            // all layer-1 A reads done
    #pragma unroll
    for (int cb = 0; cb < 2; ++cb) {
        #pragma unroll
        for (int r = 0; r < 4; ++r) {
            float gv = gelu_exact(acc[cb][r]);
            unsigned short h = f2bf(gv);
            int row = rowg + (lane >> 4) * 4 + r;
            int col = colg0 + cb * 16 + l15;
            Ahi[row * AS + col] = h;
            Alo[row * AS + col] = f2bf(gv - bf2f(h));
        }
    }
    __syncthreads();                            // h tile complete

    // ---- layer 2: out = h @ W2 + b2
    #pragma unroll
    for (int cb = 0; cb < 2; ++cb) {
        float bv = b2[colg0 + cb * 16 + l15];
        acc[cb] = (f32x4){bv, bv, bv, bv};
    }
    #pragma unroll
    for (int kk = 0; kk < 128; kk += 32) {
        bf16x8 ah = *(const bf16x8*)&Ahi[rowg * AS + l15 * AS + kk + kofs];
        bf16x8 al = *(const bf16x8*)&Alo[rowg * AS + l15 * AS + kk + kofs];
        #pragma unroll
        for (int cb = 0; cb < 2; ++cb) {
            const unsigned short* wp = wt1h + 32768 + (size_t)(colg0 + cb * 16 + l15) * 128 + kk + kofs;
            bf16x8 bh = *(const bf16x8*)wp;
            bf16x8 bl = *(const bf16x8*)(wp + 16384);
            acc[cb] = __builtin_amdgcn_mfma_f32_16x16x32_bf16(ah, bh, acc[cb], 0, 0, 0);
            acc[cb] = __builtin_amdgcn_mfma_f32_16x16x32_bf16(ah, bl, acc[cb], 0, 0, 0);
            acc[cb] = __builtin_amdgcn_mfma_f32_16x16x32_bf16(al, bh, acc[cb], 0, 0, 0);
        }
    }
    // ---- store: lanes cover 16 consecutive cols (64B segments x 4 row-groups)
    const size_t orow0 = (size_t)b * Gn + (size_t)chunk * QB + rowg + (lane >> 4) * 4;
    #pragma unroll
    for (int cb = 0; cb < 2; ++cb) {
        #pragma unroll
        for (int r = 0; r < 4; ++r) {
            out[(orow0 + r) * Cn + colg0 + cb * 16 + l15] = acc[cb][r];
        }
    }
}

// ---------------------------------------------------------------------------
extern "C" void kernel_launch(void* const* d_in, const int* in_sizes, int n_in,
                              void* d_out, int out_size, void* d_ws, size_t ws_size,
                              hipStream_t stream) {
    const float* xyz  = (const float*)d_in[0];
    const float* feat = (const float*)d_in[1];
    const float* W1   = (const float*)d_in[2];
    const float* b1   = (const float*)d_in[3];
    const float* W2   = (const float*)d_in[4];
    const float* b2   = (const float*)d_in[5];
    float* out = (float*)d_out;
    unsigned short* wt = (unsigned short*)d_ws;    // 128 KB: Wt1 hi/lo, Wt2 hi/lo

    prep_w<<<64, 256, 0, stream>>>(W1, W2, wt);
    fused_kernel<<<512, 1024, 0, stream>>>(xyz, feat, b1, b2, wt, out);
}

// Round 5
// 156.779 us; speedup vs baseline: 5.9689x; 5.9689x over previous
//
#include <hip/hip_runtime.h>
#include <math.h>

#define Bn 16
#define Gn 2048
#define Cn 128
#define Kn 16
#define QB 32       // queries per block
#define AS 136      // A-tile row stride in bf16 elems: 272B = 17*16B (aligned, 2-way banks)

typedef __attribute__((ext_vector_type(8))) short bf16x8;
typedef __attribute__((ext_vector_type(4))) float f32x4;

__device__ __forceinline__ unsigned short f2bf(float x) {   // RNE fp32->bf16
    unsigned int u = __float_as_uint(x);
    unsigned int r = (u + 0x7fffu + ((u >> 16) & 1u)) >> 16;
    return (unsigned short)r;
}
__device__ __forceinline__ float bf2f(unsigned short h) {
    return __uint_as_float(((unsigned int)h) << 16);
}

__device__ __forceinline__ float med3f(float a, float b, float c) {
#if __has_builtin(__builtin_amdgcn_fmed3f)
    return __builtin_amdgcn_fmed3f(a, b, c);
#else
    return fmaxf(fminf(a, b), fminf(fmaxf(a, b), c));
#endif
}

// BIT-IDENTICAL in every phase (fp-consistent ranking incl. tie detection).
__device__ __forceinline__ float dist2(const float4 me, const float4 p) {
    float dot = fmaf(me.z, p.z, fmaf(me.y, p.y, me.x * p.x));
    return fmaf(-2.0f, dot, me.w + p.w);
}

__device__ __forceinline__ void ins16(float (&d)[16], float v) {
    float prev = d[0];
    d[0] = fminf(d[0], v);
    #pragma unroll
    for (int t = 1; t < 16; ++t) { float cur = d[t]; d[t] = med3f(v, prev, cur); prev = cur; }
}

// exact bitonic min-merge of sorted d[16] across the 16 lanes of a group
__device__ __forceinline__ void merge16(float (&d)[16]) {
    #pragma unroll
    for (int m = 1; m < 16; m <<= 1) {
        float e[16];
        #pragma unroll
        for (int t = 0; t < 16; ++t) e[t] = __shfl_xor(d[t], m);
        float x[16];
        #pragma unroll
        for (int t = 0; t < 16; ++t) x[t] = fminf(d[t], e[15 - t]);
        #pragma unroll
        for (int k = 8; k; k >>= 1) {
            #pragma unroll
            for (int t = 0; t < 16; ++t)
                if (!(t & k)) {
                    float lo = fminf(x[t], x[t + k]);
                    float hi = fmaxf(x[t], x[t + k]);
                    x[t] = lo; x[t + k] = hi;
                }
        }
        #pragma unroll
        for (int t = 0; t < 16; ++t) d[t] = x[t];
    }
}

__device__ __forceinline__ float gelu_exact(float x) {
    return 0.5f * x * (1.0f + erff(x * 0.70710678118654752440f));
}

// ---------------------------------------------------------------------------
// prep_w: W[k][n] fp32 -> Wt[n][k] split bf16 (hi/lo) in workspace.
// ws layout (ushorts): Wt1_hi[128*128] | Wt1_lo | Wt2_hi | Wt2_lo  (128 KB)
// ---------------------------------------------------------------------------
__global__ __launch_bounds__(256) void prep_w(const float* __restrict__ W1,
                                              const float* __restrict__ W2,
                                              unsigned short* __restrict__ ws) {
    int t = blockIdx.x * 256 + threadIdx.x;     // 0..16383 (grid 64)
    if (t < 16384) {
        int k = t >> 7, n = t & 127;
        float w = W1[t];
        unsigned short h = f2bf(w);
        unsigned short l = f2bf(w - bf2f(h));   // Dekker split: w-hi exact in fp32
        ws[n * 128 + k]          = h;
        ws[16384 + n * 128 + k]  = l;
        w = W2[t];
        h = f2bf(w);
        l = f2bf(w - bf2f(h));
        ws[32768 + n * 128 + k]  = h;
        ws[49152 + n * 128 + k]  = l;
    }
}

// ---------------------------------------------------------------------------
// Fully fused: KNN (sample->filter->select) + gather/L2-pool + MFMA MLP.
// 1024 blocks x 512 threads; b = x&15; chunk = x>>4 (0..63); 32 q/block.
// 16 lanes per query; each lane owns a 128-point segment; survivors kept as
// a 4x u32 REGISTER bitmask (scan-order bits; decode h=base+((p+c)&127)).
// LDS 34816 B = union(pts 32KB, Ahi/Alo 17KB) | outb 1KB @32768 | tieb 1KB
//   -> LDS allows 4 blocks/CU; grid 1024 = 4/CU -> up to 32 waves/CU if
//      VGPR <= 64. NO min-waves launch bound (R4 lesson: forced cap = spills).
// MLP: split-bf16 MFMA 16x16x32 (Ahi*Bhi + Ahi*Blo + Alo*Bhi, err ~2^-17).
// ---------------------------------------------------------------------------
__global__ __launch_bounds__(512) void fused_kernel(const float* __restrict__ xyz,
                                                    const float* __restrict__ feat,
                                                    const float* __restrict__ b1,
                                                    const float* __restrict__ b2,
                                                    const unsigned short* __restrict__ wt,
                                                    float* __restrict__ out) {
    __shared__ __align__(16) float smem0[8704];       // 34816 B
    float4* pts = reinterpret_cast<float4*>(smem0);   // [2048] xyz + |p|^2 (0..32768)
    unsigned short* Ahi = reinterpret_cast<unsigned short*>(smem0);  // [32][AS] 0..8704
    unsigned short* Alo = Ahi + QB * AS;                             // 8704..17408
    unsigned short* outb = reinterpret_cast<unsigned short*>(smem0) + 16384;  // byte 32768, [32][16]
    unsigned short* tieb = outb + QB * 16;                                    // byte 33792, [32][16]

    const int x     = blockIdx.x;
    const int b     = x & 15;
    const int chunk = x >> 4;                       // 0..63
    const int tid   = threadIdx.x;                  // 0..511
    const int lane  = tid & 63;
    const int w     = tid >> 6;                     // 0..7
    const int sub   = lane & 15;                    // lane within 16-lane group
    const int qg    = lane >> 4;                    // query group within wave (0..3)
    const int q     = w * 4 + qg;                   // 0..31
    const int g     = chunk * QB + q;

    // ---- stage xyz + |p|^2
    const float* xb = xyz + (size_t)b * Gn * 3;
    for (int i = tid; i < Gn; i += 512) {
        float px = xb[i * 3 + 0], py = xb[i * 3 + 1], pz = xb[i * 3 + 2];
        pts[i] = make_float4(px, py, pz, px * px + py * py + pz * pz);
    }
    __syncthreads();

    const float4 me = pts[g];
    const int base = sub << 7;                      // lane's 128-point segment
    const int c    = (37 * sub) & 127;              // bank stagger

    // ---- phase A: top16 of 512-sample (32/lane) -> conservative T0
    float d[16];
    #pragma unroll
    for (int t = 0; t < 16; ++t) d[t] = INFINITY;
    for (int j = 0; j < 32; j += 4) {
        float4 p0 = pts[base + ((j + 0 + c) & 127)];
        float4 p1 = pts[base + ((j + 1 + c) & 127)];
        float4 p2 = pts[base + ((j + 2 + c) & 127)];
        float4 p3 = pts[base + ((j + 3 + c) & 127)];
        ins16(d, dist2(me, p0)); ins16(d, dist2(me, p1));
        ins16(d, dist2(me, p2)); ins16(d, dist2(me, p3));
    }
    merge16(d);
    const float T0 = d[15];

    // ---- phase B: filter scan -> register bitmask (scan-order bits, exact)
    unsigned mw[4];
    #pragma unroll
    for (int wd = 0; wd < 4; ++wd) {
        unsigned m = 0;
        #pragma unroll
        for (int j = 0; j < 32; j += 4) {
            int t0 = wd * 32 + j;
            float4 p0 = pts[base + ((t0 + 0 + c) & 127)];
            float4 p1 = pts[base + ((t0 + 1 + c) & 127)];
            float4 p2 = pts[base + ((t0 + 2 + c) & 127)];
            float4 p3 = pts[base + ((t0 + 3 + c) & 127)];
            m |= (dist2(me, p0) <= T0) ? (1u << (j + 0)) : 0u;
            m |= (dist2(me, p1) <= T0) ? (1u << (j + 1)) : 0u;
            m |= (dist2(me, p2) <= T0) ? (1u << (j + 2)) : 0u;
            m |= (dist2(me, p3) <= T0) ? (1u << (j + 3)) : 0u;
        }
        mw[wd] = m;
    }
    unsigned long long blo = mw[0] | ((unsigned long long)mw[1] << 32);
    unsigned long long bhi = mw[2] | ((unsigned long long)mw[3] << 32);

    // ---- phase C: exact top16 of survivors (own bits, no cross-lane) -> exact T
    #pragma unroll
    for (int t = 0; t < 16; ++t) d[t] = INFINITY;
    {
        unsigned long long m = blo;
        while (m) {
            int p = __builtin_ctzll(m); m &= m - 1;
            int h = base + ((p + c) & 127);
            ins16(d, dist2(me, pts[h]));
        }
        m = bhi;
        while (m) {
            int p = 64 + __builtin_ctzll(m); m &= m - 1;
            int h = base + ((p + c) & 127);
            ins16(d, dist2(me, pts[h]));
        }
    }
    merge16(d);
    const float T = d[15];

    // ---- phase D: emit index set (group-max rounds, INF padding; ballots)
    int myc = __popcll(blo) + __popcll(bhi);
    int mymax = myc;
    #pragma unroll
    for (int m = 1; m < 16; m <<= 1) {
        int o = __shfl_xor(mymax, m);
        mymax = (o > mymax) ? o : mymax;
    }
    const unsigned lowm = (1u << sub) - 1;
    const int shft = lane & 48;                     // group base bit
    int nl = 0, nt = 0;
    for (int i = 0; i < mymax; ++i) {
        int h = 0; float v = INFINITY;
        if ((blo | bhi) != 0ull) {
            int p;
            if (blo) { p = __builtin_ctzll(blo); blo &= blo - 1; }
            else     { p = 64 + __builtin_ctzll(bhi); bhi &= bhi - 1; }
            h = base + ((p + c) & 127);
            v = dist2(me, pts[h]);
        }
        bool pl = (v < T), pt = (v == T);
        unsigned long long ml = __ballot(pl);
        unsigned long long mt = __ballot(pt);
        unsigned gml = (unsigned)(ml >> shft) & 0xFFFFu;
        unsigned gmt = (unsigned)(mt >> shft) & 0xFFFFu;
        if (pl) outb[q * 16 + nl + __popc(gml & lowm)] = (unsigned short)h;  // nl_total <= 15
        if (pt) { int pp = nt + __popc(gmt & lowm); if (pp < 16) tieb[q * 16 + pp] = (unsigned short)h; }
        nl += __popc(gml);
        nt += __popc(gmt);
    }
    if (sub == 0) {
        int mfill = nl;                              // < 16
        int need  = 16 - mfill;
        int tc = (nt > 16) ? 16 : nt;
        for (int s = 0; s < need; ++s) {
            int best = 0x7fffffff, bp = -1;
            for (int u = 0; u < tc; ++u) {
                int vv = tieb[q * 16 + u];
                if (vv < best) { best = vv; bp = u; }
            }
            if (bp >= 0) { tieb[q * 16 + bp] = 0xFFFF; outb[q * 16 + mfill + s] = (unsigned short)best; }
        }
    }
    __syncthreads();                                 // pts dead; outb ready (above pts window)

    // ---- gather + L2 pool: half-wave per query, float4 lanes (512B coalesced)
    // write pooled A directly as split-bf16 into Ahi/Alo (overlays pts region)
    const float4* fb4 = (const float4*)(feat + (size_t)b * Gn * Cn);
    const int cl = lane & 31;
    #pragma unroll
    for (int pass = 0; pass < 2; ++pass) {
        int qq = w * 4 + pass * 2 + (lane >> 5);
        float4 a = make_float4(0.f, 0.f, 0.f, 0.f);
        #pragma unroll
        for (int half = 0; half < 2; ++half) {
            int hs[8]; float4 f[8];
            #pragma unroll
            for (int k = 0; k < 8; ++k) hs[k] = outb[qq * 16 + half * 8 + k];
            #pragma unroll
            for (int k = 0; k < 8; ++k) f[k] = fb4[(size_t)hs[k] * 32 + cl];
            #pragma unroll
            for (int k = 0; k < 8; ++k) {
                a.x = fmaf(f[k].x, f[k].x, a.x);
                a.y = fmaf(f[k].y, f[k].y, a.y);
                a.z = fmaf(f[k].z, f[k].z, a.z);
                a.w = fmaf(f[k].w, f[k].w, a.w);
            }
        }
        float r0 = sqrtf(a.x), r1 = sqrtf(a.y), r2 = sqrtf(a.z), r3 = sqrtf(a.w);
        unsigned short h0 = f2bf(r0), h1 = f2bf(r1), h2 = f2bf(r2), h3 = f2bf(r3);
        ushort4 hv = make_ushort4(h0, h1, h2, h3);
        ushort4 lv = make_ushort4(f2bf(r0 - bf2f(h0)), f2bf(r1 - bf2f(h1)),
                                  f2bf(r2 - bf2f(h2)), f2bf(r3 - bf2f(h3)));
        *(ushort4*)&Ahi[qq * AS + cl * 4] = hv;
        *(ushort4*)&Alo[qq * AS + cl * 4] = lv;
    }
    __syncthreads();

    // ---- MLP via split-bf16 MFMA ------------------------------------------
    // wave w: rows rowg..rowg+15 (rowg=(w&1)*16), cols colg0..colg0+31
    // A-frag: lane l -> A[rowg+(l&15)][kk + (l>>4)*8 + j]  (contiguous bf16x8)
    // B-frag: lane l -> Wt[colg0+cb*16+(l&15)][kk + (l>>4)*8 + j] (contiguous)
    // C/D:    lane l, reg r -> C[(l>>4)*4 + r][l&15]   (m89-verified)
    const int l15  = lane & 15;
    const int kofs = (lane >> 4) * 8;
    const int rowg = (w & 1) * 16;
    const int colg0 = (w >> 1) * 32;
    const unsigned short* wt1h = wt;            // +16384: lo; +32768: W2 hi; +49152: W2 lo
    f32x4 acc[2];

    // ---- layer 1: h = gelu(pooled @ W1 + b1)
    #pragma unroll
    for (int cb = 0; cb < 2; ++cb) {
        float bv = b1[colg0 + cb * 16 + l15];
        acc[cb] = (f32x4){bv, bv, bv, bv};
    }
    #pragma unroll
    for (int kk = 0; kk < 128; kk += 32) {
        bf16x8 ah = *(const bf16x8*)&Ahi[rowg * AS + l15 * AS + kk + kofs];
        bf16x8 al = *(const bf16x8*)&Alo[rowg * AS + l15 * AS + kk + kofs];
        #pragma unroll
        for (int cb = 0; cb < 2; ++cb) {
            const unsigned short* wp = wt1h + (size_t)(colg0 + cb * 16 + l15) * 128 + kk + kofs;
            bf16x8 bh = *(const bf16x8*)wp;
            bf16x8 bl = *(const bf16x8*)(wp + 16384);
            acc[cb] = __builtin_amdgcn_mfma_f32_16x16x32_bf16(ah, bh, acc[cb], 0, 0, 0);
            acc[cb] = __builtin_amdgcn_mfma_f32_16x16x32_bf16(ah, bl, acc[cb], 0, 0, 0);
            acc[cb] = __builtin_amdgcn_mfma_f32_16x16x32_bf16(al, bh, acc[cb], 0, 0, 0);
        }
    }
    __syncthreads();                            // all layer-1 A reads done
    #pragma unroll
    for (int cb = 0; cb < 2; ++cb) {
        #pragma unroll
        for (int r = 0; r < 4; ++r) {
            float gv = gelu_exact(acc[cb][r]);
            unsigned short h = f2bf(gv);
            int row = rowg + (lane >> 4) * 4 + r;
            int col = colg0 + cb * 16 + l15;
            Ahi[row * AS + col] = h;
            Alo[row * AS + col] = f2bf(gv - bf2f(h));
        }
    }
    __syncthreads();                            // h tile complete

    // ---- layer 2: out = h @ W2 + b2
    #pragma unroll
    for (int cb = 0; cb < 2; ++cb) {
        float bv = b2[colg0 + cb * 16 + l15];
        acc[cb] = (f32x4){bv, bv, bv, bv};
    }
    #pragma unroll
    for (int kk = 0; kk < 128; kk += 32) {
        bf16x8 ah = *(const bf16x8*)&Ahi[rowg * AS + l15 * AS + kk + kofs];
        bf16x8 al = *(const bf16x8*)&Alo[rowg * AS + l15 * AS + kk + kofs];
        #pragma unroll
        for (int cb = 0; cb < 2; ++cb) {
            const unsigned short* wp = wt1h + 32768 + (size_t)(colg0 + cb * 16 + l15) * 128 + kk + kofs;
            bf16x8 bh = *(const bf16x8*)wp;
            bf16x8 bl = *(const bf16x8*)(wp + 16384);
            acc[cb] = __builtin_amdgcn_mfma_f32_16x16x32_bf16(ah, bh, acc[cb], 0, 0, 0);
            acc[cb] = __builtin_amdgcn_mfma_f32_16x16x32_bf16(ah, bl, acc[cb], 0, 0, 0);
            acc[cb] = __builtin_amdgcn_mfma_f32_16x16x32_bf16(al, bh, acc[cb], 0, 0, 0);
        }
    }
    // ---- store: lanes cover 16 consecutive cols (64B segments x 4 row-groups)
    const size_t orow0 = (size_t)b * Gn + (size_t)chunk * QB + rowg + (lane >> 4) * 4;
    #pragma unroll
    for (int cb = 0; cb < 2; ++cb) {
        #pragma unroll
        for (int r = 0; r < 4; ++r) {
            out[(orow0 + r) * Cn + colg0 + cb * 16 + l15] = acc[cb][r];
        }
    }
}

// ---------------------------------------------------------------------------
extern "C" void kernel_launch(void* const* d_in, const int* in_sizes, int n_in,
                              void* d_out, int out_size, void* d_ws, size_t ws_size,
                              hipStream_t stream) {
    const float* xyz  = (const float*)d_in[0];
    const float* feat = (const float*)d_in[1];
    const float* W1   = (const float*)d_in[2];
    const float* b1   = (const float*)d_in[3];
    const float* W2   = (const float*)d_in[4];
    const float* b2   = (const float*)d_in[5];
    float* out = (float*)d_out;
    unsigned short* wt = (unsigned short*)d_ws;    // 128 KB: Wt1 hi/lo, Wt2 hi/lo

    prep_w<<<64, 256, 0, stream>>>(W1, W2, wt);
    fused_kernel<<<1024, 512, 0, stream>>>(xyz, feat, b1, b2, wt, out);
}